// Round 4
// baseline (453.173 us; speedup 1.0000x reference)
//
#include <hip/hip_runtime.h>
#include <hip/hip_bf16.h>
#include <math.h>

#define NN 2708
#define IC 1433
#define OC 128

// ---------------- zero workspace ----------------
__global__ __launch_bounds__(256) void zero_ws(float* ws, int n) {
  int i = blockIdx.x * 256 + threadIdx.x;
  if (i < n) ws[i] = 0.f;
}

// ---------------- w1 = W^T a1, w2 = W^T a2 (fp64 accumulate) ----------------
__global__ __launch_bounds__(256) void wvec(const float* __restrict__ W, const float* __restrict__ a1,
                                            const float* __restrict__ a2,
                                            double* __restrict__ w1, double* __restrict__ w2) {
  int c = blockIdx.x * 256 + threadIdx.x;
  if (c >= IC) return;
  double s1 = 0.0, s2 = 0.0;
  for (int o = 0; o < OC; o++) {
    double w = (double)W[(size_t)o * IC + c];   // coalesced across c
    s1 = fma(w, (double)a1[o], s1);
    s2 = fma(w, (double)a2[o], s2);
  }
  w1[c] = s1; w2[c] = s2;
}

// ---------------- k1 = X@w1, k2 = X@w2 (fp64), one wave per row ----------------
__global__ __launch_bounds__(256) void xw(const float* __restrict__ X, const double* __restrict__ w1,
                                          const double* __restrict__ w2,
                                          double* __restrict__ k1, double* __restrict__ k2) {
  __shared__ double w1s[IC];
  __shared__ double w2s[IC];
  const int t = threadIdx.x;
  for (int c = t; c < IC; c += 256) { w1s[c] = w1[c]; w2s[c] = w2[c]; }
  __syncthreads();
  const int wave = t >> 6, lane = t & 63;
  const int i = blockIdx.x * 4 + wave;
  if (i >= NN) return;
  const float* Xi = X + (size_t)i * IC;
  double s1 = 0.0, s2 = 0.0;
  for (int c = lane; c < IC; c += 64) {
    double x = (double)Xi[c];
    s1 = fma(x, w1s[c], s1);
    s2 = fma(x, w2s[c], s2);
  }
  for (int o = 32; o; o >>= 1) { s1 += __shfl_down(s1, o, 64); s2 += __shfl_down(s2, o, 64); }
  if (lane == 0) { k1[i] = s1; k2[i] = s2; }
}

// ---------------- K = X @ W^T (fp32, split-K 4-way via atomicAdd) ----------------
__global__ __launch_bounds__(256) void gemmK(const float* __restrict__ X, const float* __restrict__ W,
                                             float* __restrict__ K) {
  __shared__ float Xs[16][32];
  __shared__ float Ws[32][132];   // +4 pad
  const int t  = threadIdx.x;
  const int rb = blockIdx.x * 16;
  const int ks = blockIdx.y * 359;
  const int ke = min(IC, ks + 359);
  float acc[2][4] = {{0.f,0.f,0.f,0.f},{0.f,0.f,0.f,0.f}};
  const int col_base = (t & 31) * 4;
  const int row_base = (t >> 5) * 2;
  for (int kb = ks; kb < ke; kb += 32) {
    for (int idx = t; idx < 512; idx += 256) {
      int r = idx >> 5, c = idx & 31;
      int gr = rb + r, gc = kb + c;
      Xs[r][c] = (gr < NN && gc < ke) ? X[(size_t)gr * IC + gc] : 0.f;
    }
    for (int idx = t; idx < 4096; idx += 256) {
      int o = idx >> 5, c = idx & 31;
      int gc = kb + c;
      Ws[c][o] = (gc < ke) ? W[(size_t)o * IC + gc] : 0.f;
    }
    __syncthreads();
#pragma unroll
    for (int kk = 0; kk < 32; kk++) {
      float x0 = Xs[row_base][kk];
      float x1 = Xs[row_base + 1][kk];
      const float4 w4 = *reinterpret_cast<const float4*>(&Ws[kk][col_base]);
      acc[0][0] = fmaf(x0, w4.x, acc[0][0]);
      acc[0][1] = fmaf(x0, w4.y, acc[0][1]);
      acc[0][2] = fmaf(x0, w4.z, acc[0][2]);
      acc[0][3] = fmaf(x0, w4.w, acc[0][3]);
      acc[1][0] = fmaf(x1, w4.x, acc[1][0]);
      acc[1][1] = fmaf(x1, w4.y, acc[1][1]);
      acc[1][2] = fmaf(x1, w4.z, acc[1][2]);
      acc[1][3] = fmaf(x1, w4.w, acc[1][3]);
    }
    __syncthreads();
  }
#pragma unroll
  for (int r = 0; r < 2; r++) {
    int gr = rb + row_base + r;
    if (gr < NN) {
      float* dst = &K[(size_t)gr * OC + col_base];
      atomicAdd(dst + 0, acc[r][0]);
      atomicAdd(dst + 1, acc[r][1]);
      atomicAdd(dst + 2, acc[r][2]);
      atomicAdd(dst + 3, acc[r][3]);
    }
  }
}

// ---------------- u1 = U^T@k1, s = U^T@1 (fp64, column reduction + atomics) ----------------
__global__ __launch_bounds__(256) void ut_reduce(const float* __restrict__ U, const double* __restrict__ k1,
                                                 double* __restrict__ u1, double* __restrict__ s) {
  int c  = blockIdx.x * 256 + threadIdx.x;
  int r0 = blockIdx.y * 64;
  int r1 = min(NN, r0 + 64);
  if (c >= NN) return;
  double au = 0.0, as = 0.0;
  for (int r = r0; r < r1; r++) {
    double v = (double)U[(size_t)r * NN + c];   // coalesced across c
    au = fma(v, k1[r], au);
    as += v;
  }
  atomicAdd(&u1[c], au);
  atomicAdd(&s[c], as);
}

// ---------------- p = U@(lmbd*u1), q = U@(lmbd*s) (fp64), one wave per row ----------------
__global__ __launch_bounds__(256) void uv_kernel(const float* __restrict__ U, const float* __restrict__ lmbd,
                                                 const double* __restrict__ u1, const double* __restrict__ s,
                                                 double* __restrict__ p, double* __restrict__ q) {
  const int t = threadIdx.x;
  const int wave = t >> 6, lane = t & 63;
  const int r = blockIdx.x * 4 + wave;
  if (r >= NN) return;
  const float* Ur = U + (size_t)r * NN;
  double ap = 0.0, aq = 0.0;
  for (int c = lane; c < NN; c += 64) {
    double u = (double)Ur[c];
    double l = (double)lmbd[c];
    ap = fma(u, l * u1[c], ap);
    aq = fma(u, l * s[c], aq);
  }
  for (int o = 32; o; o >>= 1) { ap += __shfl_down(ap, o, 64); aq += __shfl_down(aq, o, 64); }
  if (lane == 0) { p[r] = ap; q[r] = aq; }
}

// ---------------- fused masked softmax(|p_i + q_i*k2_j|) @ K, one block per row ----------------
__global__ __launch_bounds__(256) void softmaxH(const int* __restrict__ A, const double* __restrict__ k2,
                                                const double* __restrict__ p, const double* __restrict__ q,
                                                const float* __restrict__ K, float* __restrict__ H) {
  __shared__ double k2s[NN];     // 21.7 KB
  __shared__ float  wl[NN];      // 10.8 KB
  __shared__ int    jl[NN];      // 10.8 KB
  __shared__ float  hpart[2][128];
  __shared__ double red[4];
  __shared__ int    nnz;
  __shared__ double m_sh, sum_sh;

  const int i = blockIdx.x;
  const int t = threadIdx.x;
  const int wave = t >> 6, lane = t & 63;

  for (int j = t; j < NN; j += 256) k2s[j] = k2[j];
  if (t == 0) nnz = 0;
  const double pi = p[i], qi = q[i];
  const int* Arow = A + (size_t)i * NN;
  __syncthreads();

  // pass 1: masked row max (fp64 logits)
  double m = -1e300;
  for (int j = t; j < NN; j += 256) {
    int a = Arow[j];
    if (a != 0) {
      double e = fabs(fma(qi, k2s[j], pi));
      m = fmax(m, e);
    }
  }
  for (int o = 32; o; o >>= 1) m = fmax(m, __shfl_down(m, o, 64));
  if (lane == 0) red[wave] = m;
  __syncthreads();
  if (t == 0) m_sh = fmax(fmax(red[0], red[1]), fmax(red[2], red[3]));
  __syncthreads();
  const double mi = m_sh;

  // pass 2: exp weights; compact nonzero contributions (softmax near-one-hot)
  double sumw = 0.0;
  for (int j = t; j < NN; j += 256) {
    int a = Arow[j];
    if (a != 0) {
      double arg = fabs(fma(qi, k2s[j], pi)) - mi;   // <= 0, exact in fp64
      float w = __expf((float)arg);
      sumw += (double)w;
      if (w > 1e-12f) { int pos = atomicAdd(&nnz, 1); jl[pos] = j; wl[pos] = w; }
    }
  }
  for (int o = 32; o; o >>= 1) sumw += __shfl_down(sumw, o, 64);
  if (lane == 0) red[wave] = sumw;
  __syncthreads();
  if (t == 0) sum_sh = (red[0] + red[1]) + (red[2] + red[3]);
  __syncthreads();

  // H[i] = sum_j w_j K[j] / sumw over compacted list
  const int nn = nnz;
  const float inv = (float)(1.0 / sum_sh);
  const int ch = t & 127, g = t >> 7;
  float hacc = 0.f;
  for (int it = g; it < nn; it += 2)
    hacc = fmaf(wl[it], K[(size_t)jl[it] * OC + ch], hacc);
  hpart[g][ch] = hacc;
  __syncthreads();
  if (t < 128) H[(size_t)i * OC + t] = (hpart[0][t] + hpart[1][t]) * inv;
}

extern "C" void kernel_launch(void* const* d_in, const int* in_sizes, int n_in,
                              void* d_out, int out_size, void* d_ws, size_t ws_size,
                              hipStream_t stream) {
  const float* X    = (const float*)d_in[0];
  const int*   A    = (const int*)d_in[1];
  const float* U    = (const float*)d_in[2];
  const float* W    = (const float*)d_in[3];
  const float* a1   = (const float*)d_in[4];
  const float* a2   = (const float*)d_in[5];
  const float* lmbd = (const float*)d_in[6];
  float* H = (float*)d_out;   // fp32 output — the reference's output dtype

  float* ws = (float*)d_ws;
  float*  K   = ws;                               // NN*OC floats
  double* dbl = (double*)(ws + (size_t)NN * OC);  // 8-byte aligned
  double* k1  = dbl;                              // NN
  double* k2  = k1 + NN;                          // NN
  double* u1  = k2 + NN;                          // NN
  double* sC  = u1 + NN;                          // NN
  double* p   = sC + NN;                          // NN
  double* q   = p  + NN;                          // NN
  double* w1  = q  + NN;                          // IC
  double* w2  = w1 + IC;                          // IC

  const int ndbl = 6 * NN + 2 * IC;
  const int ztot = NN * OC + 2 * ndbl;            // zero K + all double scratch
  zero_ws<<<(ztot + 255) / 256, 256, 0, stream>>>(ws, ztot);
  wvec<<<(IC + 255) / 256, 256, 0, stream>>>(W, a1, a2, w1, w2);
  xw<<<NN / 4, 256, 0, stream>>>(X, w1, w2, k1, k2);
  gemmK<<<dim3((NN + 15) / 16, 4), 256, 0, stream>>>(X, W, K);
  ut_reduce<<<dim3((NN + 255) / 256, (NN + 63) / 64), 256, 0, stream>>>(U, k1, u1, sC);
  uv_kernel<<<NN / 4, 256, 0, stream>>>(U, lmbd, u1, sC, p, q);
  softmaxH<<<NN, 256, 0, stream>>>(A, k2, p, q, K, H);
}